// Round 3
// baseline (455.755 us; speedup 1.0000x reference)
//
#include <hip/hip_runtime.h>

// Quaternion normalization: x (65536 x 1024 fp32) = 16M groups of 4 floats;
// each group scaled by 1/norm (norm==0 -> pass through).
// Pure streaming: 256 MiB in + 256 MiB out, floor ~82 us at 6.3 TB/s.
// R3: nontemporal via native ext_vector float4 (HIP float4 is a class and
// __builtin_nontemporal_* rejects it) + 2 quats/thread for MLP.

typedef float v4f __attribute__((ext_vector_type(4)));

__global__ __launch_bounds__(256) void quat_normalize_kernel(
    const v4f* __restrict__ x, v4f* __restrict__ out, int n_quats) {
    int i = (blockIdx.x * blockDim.x + threadIdx.x) * 2;
    if (i + 1 < n_quats) {
        v4f a = __builtin_nontemporal_load(&x[i]);
        v4f b = __builtin_nontemporal_load(&x[i + 1]);
        float sa = a.x * a.x + a.y * a.y + a.z * a.z + a.w * a.w;
        float sb = b.x * b.x + b.y * b.y + b.z * b.z + b.w * b.w;
        float ra = (sa == 0.0f) ? 1.0f : rsqrtf(sa);
        float rb = (sb == 0.0f) ? 1.0f : rsqrtf(sb);
        a *= ra;
        b *= rb;
        __builtin_nontemporal_store(a, &out[i]);
        __builtin_nontemporal_store(b, &out[i + 1]);
    } else if (i < n_quats) {
        v4f a = __builtin_nontemporal_load(&x[i]);
        float sa = a.x * a.x + a.y * a.y + a.z * a.z + a.w * a.w;
        float ra = (sa == 0.0f) ? 1.0f : rsqrtf(sa);
        a *= ra;
        __builtin_nontemporal_store(a, &out[i]);
    }
}

extern "C" void kernel_launch(void* const* d_in, const int* in_sizes, int n_in,
                              void* d_out, int out_size, void* d_ws, size_t ws_size,
                              hipStream_t stream) {
    const v4f* x = (const v4f*)d_in[0];
    v4f* out = (v4f*)d_out;
    int n_quats = in_sizes[0] / 4;  // 16,777,216
    const int block = 256;
    int per_block = block * 2;  // 2 quats per thread
    int grid = (n_quats + per_block - 1) / per_block;  // 32768 blocks
    quat_normalize_kernel<<<grid, block, 0, stream>>>(x, out, n_quats);
}